// Round 16
// baseline (883.387 us; speedup 1.0000x reference)
//
#include <hip/hip_runtime.h>
#include <stdint.h>

typedef unsigned short u16;
typedef __attribute__((ext_vector_type(8))) short short8;
typedef __attribute__((ext_vector_type(4))) float f32x4;

#define NE   8
#define DIN  2048
#define DOUT 8192
#define NTOK 16384

__device__ __forceinline__ u16 f2bf(float f) {
  uint32_t u = __builtin_bit_cast(uint32_t, f);
  u += 0x7FFFu + ((u >> 16) & 1u);   // RNE (inputs are finite normals)
  return (u16)(u >> 16);
}

__global__ __launch_bounds__(256) void cvt_f32_bf16(const float* __restrict__ src,
                                                    u16* __restrict__ dst, size_t n) {
  size_t i = ((size_t)blockIdx.x * 256 + threadIdx.x) * 8;
  const size_t stride = (size_t)gridDim.x * 256 * 8;
  for (; i < n; i += stride) {
    f32x4 a = *(const f32x4*)(src + i);
    f32x4 b = *(const f32x4*)(src + i + 4);
    short8 o;
    o[0] = (short)f2bf(a[0]); o[1] = (short)f2bf(a[1]);
    o[2] = (short)f2bf(a[2]); o[3] = (short)f2bf(a[3]);
    o[4] = (short)f2bf(b[0]); o[5] = (short)f2bf(b[1]);
    o[6] = (short)f2bf(b[2]); o[7] = (short)f2bf(b[3]);
    *(short8*)(dst + i) = o;
  }
}

#define GLOAD_LDS16(g, l) __builtin_amdgcn_global_load_lds( \
    (const __attribute__((address_space(1))) void*)(g),     \
    (__attribute__((address_space(3))) void*)(l), 16, 0, 0)

// ---------------------------------------------------------------------------
// r16 = r11's proven pieces (256x256 tile, 8 waves 2x4, 16x16x32, 0-conflict
// swizzles, counted vmcnt w/ r2 tail discipline, coalesced nt epilogue,
// XCD=expert mapping) + FUSED W conversion done RIGHT this time:
//  - W staged f32 -> LDS via global_load_lds (register-neutral; r9's spill
//    mode avoided), BK=32, F region double-buffered (A 32K+Bb 32K+F 64K=128K)
//  - ONE LDS->LDS convert pass per tile (4 ds_read_b128 + 16 f2bf + 2
//    swizzled ds_write_b128 per thread), after MMQ(4) so frag regs reuse;
//    once per element (r12's 8x-redundant per-fragment cvt avoided), and
//    B fragment reads stay on the verified 0-conflict bf16 path.
//  - cvt_w pre-pass DELETED (-150us wall; W f32 read once, L2-shared).
// Pipeline invariant at top of tile t: A[cur],Bb[cur] published; F[(t+1)&1]
// holds t+1's f32 (published). p1 stages A(t+1)->nxt + F[t&1]<-t+2.
// p2: VMW(4) drains {prior F4, cur A2} keeping cur F4 in flight; BAR
// publishes F(t+1)+A(t+1); MMQ(4); convert F->Bb[nxt]; LGKM0; BAR.
// Tails: t+2>=NKT -> VMW(0) (r2: counted wait would no-op); last: none.
// ---------------------------------------------------------------------------
__global__ __launch_bounds__(512, 2) void moe_gemm8(
    const u16* __restrict__ Xb, const float* __restrict__ Wf,
    const int* __restrict__ counts, const float* __restrict__ bias,
    float* __restrict__ C) {
  extern __shared__ u16 sm[];  // 65536 u16 = 128 KiB

  const int tid = threadIdx.x;
  const int l = tid & 63;
  const int wid = tid >> 6;      // 0..7
  const int wr = wid >> 2;       // 0..1  (M halves of 128)
  const int wc = wid & 3;        // 0..3  (N quarters of 64)

  // XCD-bijective swizzle: 2048 blocks, 256/XCD == tiles/expert => expert==XCD
  const int id = blockIdx.x;
  const int swz = (id & 7) * 256 + (id >> 3);
  const int e = swz >> 8;
  const int rem = swz & 255;
  const int tn = rem >> 3;       // 0..31 (8 consecutive blocks share W-panel)
  const int tm = rem & 7;        // 0..7

  int off = 0;
  for (int i = 0; i < e; ++i) off += counts[i];
  const int row0 = off + tm * 256;
  const int col0 = tn * 256;
  const size_t wbase = (size_t)e * DOUT * DIN + (size_t)col0 * DIN;

  // -- A staging (bf16, pre-swizzled source, linear gload_lds dest)
  const int rl = l >> 2;                     // row within 16-row slice
  const int q = (l & 3) ^ ((l >> 3) & 3);    // source k-granule (inverse swz)
  const int s0 = wid * 2, s1 = s0 + 1;       // 2 slices of 16 rows
  const u16* pA0 = Xb + (size_t)(row0 + s0 * 16 + rl) * DIN + q * 8;
  const u16* pA1 = Xb + (size_t)(row0 + s1 * 16 + rl) * DIN + q * 8;

  // -- F staging (f32 W, linear source AND linear dest; 4 slices of 8 rows)
  const float* pF0 = Wf + wbase + (size_t)(wid * 32 + 0 + (l >> 3)) * DIN + (l & 7) * 4;
  const float* pF1 = Wf + wbase + (size_t)(wid * 32 + 8 + (l >> 3)) * DIN + (l & 7) * 4;
  const float* pF2 = Wf + wbase + (size_t)(wid * 32 + 16 + (l >> 3)) * DIN + (l & 7) * 4;
  const float* pF3 = Wf + wbase + (size_t)(wid * 32 + 24 + (l >> 3)) * DIN + (l & 7) * 4;

  // -- fragment-read constants (16x16 layout, r3-verified swizzle)
  const int gph = (l >> 4) ^ (((l & 15) >> 1) & 3);
  const int aoff = (wr * 128 + (l & 15)) * 32 + gph * 8;
  const int boff = (wc * 64 + (l & 15)) * 32 + gph * 8;

  // -- convert-pass constants: thread -> (row cr, half ch)
  const int cr = tid >> 1, ch = tid & 1;
  const int csw = (cr >> 1) & 3;
  const int p0 = (2 * ch) ^ csw, p1 = (2 * ch + 1) ^ csw;

  f32x4 acc[8][4] = {};
  short8 a[4], b[4];

#define SMA(buf)  (sm + (buf) * 8192)            // A bf16 [2][256][32]
#define SMBb(buf) (sm + 16384 + (buf) * 8192)    // B bf16 [2][256][32]
#define SMF(fb)   (sm + 32768 + (fb) * 16384)    // B f32  [2][256][32] (u16 view)
#define STAGE_A(buf, kt) do { const int ko = (kt) * 32;     \
    GLOAD_LDS16(pA0 + ko, SMA(buf) + s0 * 512);             \
    GLOAD_LDS16(pA1 + ko, SMA(buf) + s1 * 512); } while (0)
#define STAGE_F(fb, kt) do { const int ko = (kt) * 32;      \
    GLOAD_LDS16(pF0 + ko, SMF(fb) + (wid * 32 + 0) * 64);   \
    GLOAD_LDS16(pF1 + ko, SMF(fb) + (wid * 32 + 8) * 64);   \
    GLOAD_LDS16(pF2 + ko, SMF(fb) + (wid * 32 + 16) * 64);  \
    GLOAD_LDS16(pF3 + ko, SMF(fb) + (wid * 32 + 24) * 64); } while (0)
#define RA4(buf, mb) do { _Pragma("unroll") for (int mf = 0; mf < 4; ++mf) \
    a[mf] = *(const short8*)(SMA(buf) + aoff + ((mb) + mf) * 512); } while (0)
#define RB4(buf) do { _Pragma("unroll") for (int nf = 0; nf < 4; ++nf) \
    b[nf] = *(const short8*)(SMBb(buf) + boff + nf * 512); } while (0)
#define CONVERT(fb, bbuf) do {                                        \
    const float* fr = (const float*)SMF(fb) + cr * 32 + ch * 16;      \
    f32x4 v0 = *(const f32x4*)(fr + 0);                               \
    f32x4 v1 = *(const f32x4*)(fr + 4);                               \
    f32x4 v2 = *(const f32x4*)(fr + 8);                               \
    f32x4 v3 = *(const f32x4*)(fr + 12);                              \
    short8 w0, w1;                                                    \
    _Pragma("unroll") for (int j = 0; j < 4; ++j) {                   \
      w0[j] = (short)f2bf(v0[j]); w0[4 + j] = (short)f2bf(v1[j]);     \
      w1[j] = (short)f2bf(v2[j]); w1[4 + j] = (short)f2bf(v3[j]);     \
    }                                                                 \
    *(short8*)(SMBb(bbuf) + cr * 32 + p0 * 8) = w0;                   \
    *(short8*)(SMBb(bbuf) + cr * 32 + p1 * 8) = w1; } while (0)
#define FENCE() asm volatile("" ::: "memory")
#define BAR() do { FENCE(); __builtin_amdgcn_s_barrier(); FENCE(); } while (0)
#define VMW(N) asm volatile("s_waitcnt vmcnt(" #N ")" ::: "memory")
#define LGKM0() asm volatile("s_waitcnt lgkmcnt(0)" ::: "memory")
#define MMQ(mb) do { __builtin_amdgcn_s_setprio(1);                                \
    _Pragma("unroll") for (int mf = 0; mf < 4; ++mf)                               \
      _Pragma("unroll") for (int nf = 0; nf < 4; ++nf)                             \
        acc[(mb) + mf][nf] =                                                       \
          __builtin_amdgcn_mfma_f32_16x16x32_bf16(a[mf], b[nf], acc[(mb) + mf][nf], 0, 0, 0); \
    __builtin_amdgcn_s_setprio(0); } while (0)

  const int NKT = DIN / 32;  // 64 K-tiles

  // prologue: A(t0), F[0]<-t0, F[1]<-t1; drain; convert t0's B; publish.
  STAGE_A(0, 0); STAGE_F(0, 0); STAGE_F(1, 1);
  VMW(0);
  BAR();
  CONVERT(0, 0);
  LGKM0();
  BAR();

  for (int kt = 0; kt < NKT; kt += 2) {
#define TILE(cur, nxt, t) do {                                          \
    const bool h1 = (t) + 1 < NKT;                                      \
    const bool h2 = (t) + 2 < NKT;                                      \
    /* p1: frag reads (published) ; stage A(t+1), F<-t+2 */             \
    RA4(cur, 0); RB4(cur);                                              \
    if (h1) STAGE_A(nxt, (t) + 1);                                      \
    if (h2) STAGE_F((t) & 1, (t) + 2);                                  \
    BAR(); MMQ(0);                                                      \
    /* p2: frag reads ; drain {prior F4, cur A2} ; publish ; convert */ \
    RA4(cur, 4);                                                        \
    if (h2) VMW(4); else if (h1) VMW(0);                                \
    BAR(); MMQ(4);                                                      \
    if (h1) { CONVERT(((t) + 1) & 1, nxt); LGKM0(); }                   \
    BAR(); } while (0)
    TILE(0, 1, kt);
    TILE(1, 0, kt + 1);
#undef TILE
  }

  // ---- epilogue: LDS repack -> coalesced nontemporal dwordx4 stores ----
  BAR();  // LDS now free scratch
  float* smf = (float*)sm;
  const int cbw = col0 + wc * 64;             // wave's 64-col span
  const int r0 = (l >> 4) << 2;               // acc row offset within frag
  const f32x4 bv4 = *(const f32x4*)(bias + (size_t)e * DOUT + cbw + (l & 15) * 4);

#pragma unroll
  for (int m = 0; m < 8; ++m) {
    float* eb = smf + (wid * 2 + (m & 1)) * 1088;   // 16x68 f32, dbuf'd
#pragma unroll
    for (int n = 0; n < 4; ++n) {
      const int c = n * 16 + (l & 15);
#pragma unroll
      for (int j = 0; j < 4; ++j)
        eb[(r0 + j) * 68 + c] = acc[m][n][j];
    }
    LGKM0();  // own writes visible (wave-private region)
    const int rbm = row0 + wr * 128 + m * 16;
#pragma unroll
    for (int i = 0; i < 4; ++i) {
      const int row = i * 4 + (l >> 4);
      f32x4 v = *(const f32x4*)(eb + row * 68 + (l & 15) * 4);
      v = v + bv4;
      __builtin_nontemporal_store(
          v, (f32x4*)(C + (size_t)(rbm + row) * DOUT + cbw + (l & 15) * 4));
    }
  }
}

// ---------------------------------------------------------------------------
// Fallback (ws too small): fused fp32->bf16 staging, 128x128 m97 structure.
// ---------------------------------------------------------------------------
__global__ __launch_bounds__(256) void moe_gemm_fused(
    const float* __restrict__ Xf, const float* __restrict__ Wf,
    const int* __restrict__ counts, const float* __restrict__ bias,
    float* __restrict__ C) {
  __shared__ __align__(16) u16 lds[2][2][128 * 32];

  const int tid = threadIdx.x;
  const int lane = tid & 63;
  const int wid = tid >> 6;
  const int wr = wid >> 1;
  const int wc = wid & 1;

  const int id = blockIdx.x;
  const int swz = (id & 7) * ((int)gridDim.x >> 3) + (id >> 3);
  const int e = swz >> 10;
  const int rem = swz & 1023;
  const int tn = rem >> 4;
  const int tml = rem & 15;

  int off = 0;
  for (int i = 0; i < e; ++i) off += counts[i];
  const int row0 = off + tml * 128;
  const int col0 = tn * 128;
  const size_t wbase = (size_t)e * DOUT * DIN + (size_t)col0 * DIN;

  f32x4 acc[4][4] = {};

  auto stage = [&](int buf, int kt) {
#pragma unroll
    for (int s = 0; s < 2; ++s) {
      int i = s * 256 + tid;
      int r = i >> 2, c = i & 3;
      const float* sa = Xf + (size_t)(row0 + r) * DIN + kt * 32 + c * 8;
      const float* sb = Wf + wbase + (size_t)r * DIN + kt * 32 + c * 8;
      f32x4 a0 = *(const f32x4*)sa;
      f32x4 a1 = *(const f32x4*)(sa + 4);
      f32x4 b0 = *(const f32x4*)sb;
      f32x4 b1 = *(const f32x4*)(sb + 4);
      short8 va, vb;
#pragma unroll
      for (int j = 0; j < 4; ++j) {
        va[j] = (short)f2bf(a0[j]); va[j + 4] = (short)f2bf(a1[j]);
        vb[j] = (short)f2bf(b0[j]); vb[j + 4] = (short)f2bf(b1[j]);
      }
      *(short8*)&lds[buf][0][i * 8] = va;
      *(short8*)&lds[buf][1][i * 8] = vb;
    }
  };

  auto compute = [&](int buf) {
    const int kc = lane >> 4;
    const int rr = lane & 15;
    short8 a[4], b[4];
    const u16* lA = lds[buf][0];
    const u16* lB = lds[buf][1];
#pragma unroll
    for (int m = 0; m < 4; ++m)
      a[m] = *(const short8*)(lA + (wr * 64 + m * 16 + rr) * 32 + kc * 8);
#pragma unroll
    for (int n = 0; n < 4; ++n)
      b[n] = *(const short8*)(lB + (wc * 64 + n * 16 + rr) * 32 + kc * 8);
#pragma unroll
    for (int m = 0; m < 4; ++m)
#pragma unroll
      for (int n = 0; n < 4; ++n)
        acc[m][n] = __builtin_amdgcn_mfma_f32_16x16x32_bf16(a[m], b[n], acc[m][n], 0, 0, 0);
  };

  stage(0, 0);
  for (int kt = 0; kt < DIN / 32; ++kt) {
    __syncthreads();
    if (kt + 1 < DIN / 32) stage((kt + 1) & 1, kt + 1);
    compute(kt & 1);
  }

  const int rbase = row0 + wr * 64;
  const int cbase = col0 + wc * 64;
#pragma unroll
  for (int n = 0; n < 4; ++n) {
    const int col = cbase + n * 16 + (lane & 15);
    const float bv = bias[e * DOUT + col];
#pragma unroll
    for (int m = 0; m < 4; ++m) {
      const int r0 = rbase + m * 16 + (lane >> 4) * 4;
#pragma unroll
      for (int j = 0; j < 4; ++j)
        C[(size_t)(r0 + j) * DOUT + col] = acc[m][n][j] + bv;
    }
  }
}

extern "C" void kernel_launch(void* const* d_in, const int* in_sizes, int n_in,
                              void* d_out, int out_size, void* d_ws, size_t ws_size,
                              hipStream_t stream) {
  const float* inp = (const float*)d_in[0];
  const int* counts = (const int*)d_in[1];
  const float* weight = (const float*)d_in[2];
  const float* bias = (const float*)d_in[3];
  float* out = (float*)d_out;

  const size_t nx = (size_t)NTOK * DIN;
  const size_t need = nx * sizeof(u16);   // only X is pre-converted now

  if (ws_size >= need) {
    u16* xb = (u16*)d_ws;
    cvt_f32_bf16<<<2048, 256, 0, stream>>>(inp, xb, nx);
    const int grid = (NTOK / 256) * (DOUT / 256);  // 2048
    moe_gemm8<<<grid, 512, 131072, stream>>>(xb, weight, counts, bias, out);
  } else {
    const int grid = (NTOK / 128) * (DOUT / 128);  // 8192
    moe_gemm_fused<<<grid, 256, 0, stream>>>(inp, weight, counts, bias, out);
  }
}

// Round 17
// 715.630 us; speedup vs baseline: 1.2344x; 1.2344x over previous
//
#include <hip/hip_runtime.h>
#include <stdint.h>

typedef unsigned short u16;
typedef __attribute__((ext_vector_type(8))) short short8;
typedef __attribute__((ext_vector_type(4))) float f32x4;

#define NE   8
#define DIN  2048
#define DOUT 8192
#define NTOK 16384

__device__ __forceinline__ u16 f2bf(float f) {
  uint32_t u = __builtin_bit_cast(uint32_t, f);
  u += 0x7FFFu + ((u >> 16) & 1u);   // RNE (inputs are finite normals)
  return (u16)(u >> 16);
}

__global__ __launch_bounds__(256) void cvt_f32_bf16(const float* __restrict__ src,
                                                    u16* __restrict__ dst, size_t n) {
  size_t i = ((size_t)blockIdx.x * 256 + threadIdx.x) * 8;
  const size_t stride = (size_t)gridDim.x * 256 * 8;
  for (; i < n; i += stride) {
    // nontemporal: f32 source is never re-read — keep it out of L2/L3
    f32x4 a = __builtin_nontemporal_load((const f32x4*)(src + i));
    f32x4 b = __builtin_nontemporal_load((const f32x4*)(src + i + 4));
    short8 o;
    o[0] = (short)f2bf(a[0]); o[1] = (short)f2bf(a[1]);
    o[2] = (short)f2bf(a[2]); o[3] = (short)f2bf(a[3]);
    o[4] = (short)f2bf(b[0]); o[5] = (short)f2bf(b[1]);
    o[6] = (short)f2bf(b[2]); o[7] = (short)f2bf(b[3]);
    *(short8*)(dst + i) = o;
  }
}

#define GLOAD_LDS16(g, l) __builtin_amdgcn_global_load_lds( \
    (const __attribute__((address_space(1))) void*)(g),     \
    (__attribute__((address_space(3))) void*)(l), 16, 0, 0)

// ---------------------------------------------------------------------------
// r17 = r11 RESTORED (verified best: GEMM 562us, total ~727-730us).
// r16's fused-W reverted — fusion verdict after 3 designs (r9 spills,
// r12 per-frag cvt + conflicts, r16 cvt-pass conflicts): the 140us cvt_w
// pre-pass is strictly cheaper. K-loop = r8's 4-barrier balanced-quadrant
// schedule (6-probe-verified local optimum); staging swizzle measured
// 0 conflicts; counted vmcnt with r2 tail discipline; coalesced
// nontemporal LDS-repack epilogue (r11, -95MB write amplification).
// ---------------------------------------------------------------------------
__global__ __launch_bounds__(512, 2) void moe_gemm8(
    const u16* __restrict__ Xb, const u16* __restrict__ Wb,
    const int* __restrict__ counts, const float* __restrict__ bias,
    float* __restrict__ C) {
  extern __shared__ u16 sm[];  // 65536 u16 = 128 KiB

  const int tid = threadIdx.x;
  const int l = tid & 63;
  const int wid = tid >> 6;      // 0..7
  const int wr = wid >> 2;       // 0..1  (M halves of 128)
  const int wc = wid & 3;        // 0..3  (N quarters of 64)

  // XCD-bijective swizzle: 2048 blocks, 256/XCD == tiles/expert => expert==XCD
  const int id = blockIdx.x;
  const int swz = (id & 7) * 256 + (id >> 3);
  const int e = swz >> 8;
  const int rem = swz & 255;
  const int tn = rem >> 3;       // 0..31 (8 consecutive blocks share B-panel)
  const int tm = rem & 7;        // 0..7

  int off = 0;
  for (int i = 0; i < e; ++i) off += counts[i];
  const int row0 = off + tm * 256;
  const int col0 = tn * 256;
  const size_t wbase = (size_t)e * DOUT * DIN + (size_t)col0 * DIN;

  // -- staging per-lane constants (pre-swizzled global source, linear dest)
  const int rl = l >> 2;                     // row within 16-row slice
  const int q = (l & 3) ^ ((l >> 3) & 3);    // source k-granule (inverse swz)
  const int s0 = wid * 2, s1 = s0 + 1;       // this wave's 2 slices of 16
  const u16* pA0 = Xb + (size_t)(row0 + s0 * 16 + rl) * DIN + q * 8;
  const u16* pA1 = Xb + (size_t)(row0 + s1 * 16 + rl) * DIN + q * 8;
  const u16* pB0 = Wb + wbase + (size_t)(s0 * 16 + rl) * DIN + q * 8;
  const u16* pB1 = Wb + wbase + (size_t)(s1 * 16 + rl) * DIN + q * 8;

  // -- fragment-read per-lane constants (16x16 layout, r3-verified swizzle)
  const int f0 = ((l & 15) >> 1) & 3;
  const int gph = (l >> 4) ^ f0;             // physical granule 0..3
  const int aoff = (wr * 128 + (l & 15)) * 32 + gph * 8;
  const int boff = (wc * 64 + (l & 15)) * 32 + gph * 8;

  f32x4 acc[8][4] = {};
  short8 a[4], b[4];

#define SMA(buf, kh) (sm + (buf) * 32768 + (kh) * 8192)
#define SMB(buf, kh) (sm + (buf) * 32768 + 16384 + (kh) * 8192)
#define STAGE_A(buf, kt, kh) do { const int ko = (kt) * 64 + (kh) * 32; \
    GLOAD_LDS16(pA0 + ko, SMA(buf, kh) + s0 * 512);                     \
    GLOAD_LDS16(pA1 + ko, SMA(buf, kh) + s1 * 512); } while (0)
#define STAGE_B(buf, kt, kh) do { const int ko = (kt) * 64 + (kh) * 32; \
    GLOAD_LDS16(pB0 + ko, SMB(buf, kh) + s0 * 512);                     \
    GLOAD_LDS16(pB1 + ko, SMB(buf, kh) + s1 * 512); } while (0)
#define RA4(buf, kh, mb) do { _Pragma("unroll") for (int mf = 0; mf < 4; ++mf) \
    a[mf] = *(const short8*)(SMA(buf, kh) + aoff + ((mb) + mf) * 512); } while (0)
#define RB4(buf, kh) do { _Pragma("unroll") for (int nf = 0; nf < 4; ++nf) \
    b[nf] = *(const short8*)(SMB(buf, kh) + boff + nf * 512); } while (0)
#define FENCE() asm volatile("" ::: "memory")
#define BAR() do { FENCE(); __builtin_amdgcn_s_barrier(); FENCE(); } while (0)
#define VMW(N) asm volatile("s_waitcnt vmcnt(" #N ")" ::: "memory")
#define LGKM0() asm volatile("s_waitcnt lgkmcnt(0)" ::: "memory")
#define MMQ(mb) do { __builtin_amdgcn_s_setprio(1);                                \
    _Pragma("unroll") for (int mf = 0; mf < 4; ++mf)                               \
      _Pragma("unroll") for (int nf = 0; nf < 4; ++nf)                             \
        acc[(mb) + mf][nf] =                                                       \
          __builtin_amdgcn_mfma_f32_16x16x32_bf16(a[mf], b[nf], acc[(mb) + mf][nf], 0, 0, 0); \
    __builtin_amdgcn_s_setprio(0); } while (0)

  const int NKT = DIN / 64;  // 32 K-tiles

  // prologue: tile 0 staged (kh0 first); VMW(4) publishes kh0, kh1 in flight.
  STAGE_A(0, 0, 0); STAGE_B(0, 0, 0); STAGE_A(0, 0, 1); STAGE_B(0, 0, 1);
  VMW(4);
  BAR();

  for (int kt = 0; kt < NKT; kt += 2) {
#define TILE(cur, nxt, t) do {                                          \
    const bool hn = (t) + 1 < NKT;                                      \
    /* ph1: kh0 m0-3 (8 reads pre-bar) */                               \
    RA4(cur, 0, 0); RB4(cur, 0);                                        \
    if (hn) STAGE_A(nxt, (t) + 1, 0);                                   \
    BAR(); MMQ(0);                                                      \
    /* ph2: kh0 m4-7 (4 reads) ; publish cur-kh1 */                     \
    RA4(cur, 0, 4);                                                     \
    if (hn) { STAGE_B(nxt, (t) + 1, 0); VMW(4); } else VMW(0);          \
    BAR(); MMQ(4);                                                      \
    /* ph3: kh1 m0-3 (8 reads) */                                       \
    RA4(cur, 1, 0); RB4(cur, 1);                                        \
    if (hn) STAGE_A(nxt, (t) + 1, 1);                                   \
    BAR(); MMQ(0);                                                      \
    /* ph4: kh1 m4-7 (4 reads) ; publish next-kh0 */                    \
    RA4(cur, 1, 4);                                                     \
    if (hn) { STAGE_B(nxt, (t) + 1, 1); VMW(4); }                       \
    BAR(); MMQ(4); } while (0)
    TILE(0, 1, kt);
    TILE(1, 0, kt + 1);
#undef TILE
  }

  // ---- epilogue: LDS repack -> coalesced nontemporal dwordx4 stores ----
  BAR();  // all K-loop LDS reads complete; LDS is now free scratch
  float* smf = (float*)sm;
  const int cbw = col0 + wc * 64;             // wave's 64-col span
  const int r0 = (l >> 4) << 2;               // acc row offset within frag
  const f32x4 bv4 = *(const f32x4*)(bias + (size_t)e * DOUT + cbw + (l & 15) * 4);

#pragma unroll
  for (int m = 0; m < 8; ++m) {
    float* eb = smf + (wid * 2 + (m & 1)) * 1088;   // 16x68 f32, dbuf'd
#pragma unroll
    for (int n = 0; n < 4; ++n) {
      const int c = n * 16 + (l & 15);
#pragma unroll
      for (int j = 0; j < 4; ++j)
        eb[(r0 + j) * 68 + c] = acc[m][n][j];
    }
    LGKM0();  // own writes visible (wave-private region)
    const int rbm = row0 + wr * 128 + m * 16;
#pragma unroll
    for (int i = 0; i < 4; ++i) {
      const int row = i * 4 + (l >> 4);
      f32x4 v = *(const f32x4*)(eb + row * 68 + (l & 15) * 4);
      v = v + bv4;
      __builtin_nontemporal_store(
          v, (f32x4*)(C + (size_t)(rbm + row) * DOUT + cbw + (l & 15) * 4));
    }
  }
}

// ---------------------------------------------------------------------------
// Fallback (ws too small): fused fp32->bf16 staging, 128x128 m97 structure.
// ---------------------------------------------------------------------------
__global__ __launch_bounds__(256) void moe_gemm_fused(
    const float* __restrict__ Xf, const float* __restrict__ Wf,
    const int* __restrict__ counts, const float* __restrict__ bias,
    float* __restrict__ C) {
  __shared__ __align__(16) u16 lds[2][2][128 * 32];

  const int tid = threadIdx.x;
  const int lane = tid & 63;
  const int wid = tid >> 6;
  const int wr = wid >> 1;
  const int wc = wid & 1;

  const int id = blockIdx.x;
  const int swz = (id & 7) * ((int)gridDim.x >> 3) + (id >> 3);
  const int e = swz >> 10;
  const int rem = swz & 1023;
  const int tn = rem >> 4;
  const int tml = rem & 15;

  int off = 0;
  for (int i = 0; i < e; ++i) off += counts[i];
  const int row0 = off + tml * 128;
  const int col0 = tn * 128;
  const size_t wbase = (size_t)e * DOUT * DIN + (size_t)col0 * DIN;

  f32x4 acc[4][4] = {};

  auto stage = [&](int buf, int kt) {
#pragma unroll
    for (int s = 0; s < 2; ++s) {
      int i = s * 256 + tid;
      int r = i >> 2, c = i & 3;
      const float* sa = Xf + (size_t)(row0 + r) * DIN + kt * 32 + c * 8;
      const float* sb = Wf + wbase + (size_t)r * DIN + kt * 32 + c * 8;
      f32x4 a0 = *(const f32x4*)sa;
      f32x4 a1 = *(const f32x4*)(sa + 4);
      f32x4 b0 = *(const f32x4*)sb;
      f32x4 b1 = *(const f32x4*)(sb + 4);
      short8 va, vb;
#pragma unroll
      for (int j = 0; j < 4; ++j) {
        va[j] = (short)f2bf(a0[j]); va[j + 4] = (short)f2bf(a1[j]);
        vb[j] = (short)f2bf(b0[j]); vb[j + 4] = (short)f2bf(b1[j]);
      }
      *(short8*)&lds[buf][0][i * 8] = va;
      *(short8*)&lds[buf][1][i * 8] = vb;
    }
  };

  auto compute = [&](int buf) {
    const int kc = lane >> 4;
    const int rr = lane & 15;
    short8 a[4], b[4];
    const u16* lA = lds[buf][0];
    const u16* lB = lds[buf][1];
#pragma unroll
    for (int m = 0; m < 4; ++m)
      a[m] = *(const short8*)(lA + (wr * 64 + m * 16 + rr) * 32 + kc * 8);
#pragma unroll
    for (int n = 0; n < 4; ++n)
      b[n] = *(const short8*)(lB + (wc * 64 + n * 16 + rr) * 32 + kc * 8);
#pragma unroll
    for (int m = 0; m < 4; ++m)
#pragma unroll
      for (int n = 0; n < 4; ++n)
        acc[m][n] = __builtin_amdgcn_mfma_f32_16x16x32_bf16(a[m], b[n], acc[m][n], 0, 0, 0);
  };

  stage(0, 0);
  for (int kt = 0; kt < DIN / 32; ++kt) {
    __syncthreads();
    if (kt + 1 < DIN / 32) stage((kt + 1) & 1, kt + 1);
    compute(kt & 1);
  }

  const int rbase = row0 + wr * 64;
  const int cbase = col0 + wc * 64;
#pragma unroll
  for (int n = 0; n < 4; ++n) {
    const int col = cbase + n * 16 + (lane & 15);
    const float bv = bias[e * DOUT + col];
#pragma unroll
    for (int m = 0; m < 4; ++m) {
      const int r0 = rbase + m * 16 + (lane >> 4) * 4;
#pragma unroll
      for (int j = 0; j < 4; ++j)
        C[(size_t)(r0 + j) * DOUT + col] = acc[m][n][j] + bv;
    }
  }
}

extern "C" void kernel_launch(void* const* d_in, const int* in_sizes, int n_in,
                              void* d_out, int out_size, void* d_ws, size_t ws_size,
                              hipStream_t stream) {
  const float* inp = (const float*)d_in[0];
  const int* counts = (const int*)d_in[1];
  const float* weight = (const float*)d_in[2];
  const float* bias = (const float*)d_in[3];
  float* out = (float*)d_out;

  const size_t nx = (size_t)NTOK * DIN;
  const size_t nw = (size_t)NE * DOUT * DIN;
  const size_t need = (nx + nw) * sizeof(u16);

  if (ws_size >= need) {
    u16* xb = (u16*)d_ws;
    u16* wb = xb + nx;
    cvt_f32_bf16<<<1024, 256, 0, stream>>>(inp, xb, nx);
    cvt_f32_bf16<<<4096, 256, 0, stream>>>(weight, wb, nw);
    const int grid = (NTOK / 256) * (DOUT / 256);  // 2048
    moe_gemm8<<<grid, 512, 131072, stream>>>(xb, wb, counts, bias, out);
  } else {
    const int grid = (NTOK / 128) * (DOUT / 128);  // 8192
    moe_gemm_fused<<<grid, 256, 0, stream>>>(inp, weight, counts, bias, out);
  }
}

// Round 18
// 703.523 us; speedup vs baseline: 1.2557x; 1.0172x over previous
//
#include <hip/hip_runtime.h>
#include <stdint.h>

typedef unsigned short u16;
typedef __attribute__((ext_vector_type(8))) short short8;
typedef __attribute__((ext_vector_type(4))) float f32x4;

#define NE   8
#define DIN  2048
#define DOUT 8192
#define NTOK 16384

__device__ __forceinline__ u16 f2bf(float f) {
  uint32_t u = __builtin_bit_cast(uint32_t, f);
  u += 0x7FFFu + ((u >> 16) & 1u);   // RNE (inputs are finite normals)
  return (u16)(u >> 16);
}

__global__ __launch_bounds__(256) void cvt_f32_bf16(const float* __restrict__ src,
                                                    u16* __restrict__ dst, size_t n) {
  size_t i = ((size_t)blockIdx.x * 256 + threadIdx.x) * 8;
  const size_t stride = (size_t)gridDim.x * 256 * 8;
  for (; i < n; i += stride) {
    // nontemporal: f32 source is never re-read — keep it out of L2/L3
    f32x4 a = __builtin_nontemporal_load((const f32x4*)(src + i));
    f32x4 b = __builtin_nontemporal_load((const f32x4*)(src + i + 4));
    short8 o;
    o[0] = (short)f2bf(a[0]); o[1] = (short)f2bf(a[1]);
    o[2] = (short)f2bf(a[2]); o[3] = (short)f2bf(a[3]);
    o[4] = (short)f2bf(b[0]); o[5] = (short)f2bf(b[1]);
    o[6] = (short)f2bf(b[2]); o[7] = (short)f2bf(b[3]);
    *(short8*)(dst + i) = o;
  }
}

#define GLOAD_LDS16(g, l) __builtin_amdgcn_global_load_lds( \
    (const __attribute__((address_space(1))) void*)(g),     \
    (__attribute__((address_space(3))) void*)(l), 16, 0, 0)

// ---------------------------------------------------------------------------
// r18 = r17 with the two NON-PUBLISH barriers removed (4 -> 2 s_barrier per
// K-tile). Publish analysis: ph2's reads (kh0) were published at the PREVIOUS
// tile's ph4-BAR; ph4's reads (kh1) at ph2-BAR. The ph1/ph3 barriers guarded
// nothing -> pure convergence overhead (8 waves, 1 block/CU: every barrier
// propagates worst-wave jitter). Unlike r10 (which merged regions and let
// the compiler bunch all 24 reads ahead of both MMQs, -6%), the phase
// instruction order is preserved and pinned with sched_barrier(0) at the
// removed positions (compile-time only, zero runtime cost).
// Cross-wave DMA-overwrite hazard: every STAGE targeting region R executes
// >=1 hw barrier after ALL waves' last reads of R were CONSUMED by their MMQ
// (consumption precedes their barrier arrival) — same distance argument that
// held r8..r17 correct. vmcnt identical to r17: VMW(4)@ph2 drains cur-kh1
// (2-3 phases old), VMW(4)@ph4 drains next-kh0; last tile VMW(0)@ph2 (r2
// rule: a counted wait that would no-op races).
// ---------------------------------------------------------------------------
__global__ __launch_bounds__(512, 2) void moe_gemm8(
    const u16* __restrict__ Xb, const u16* __restrict__ Wb,
    const int* __restrict__ counts, const float* __restrict__ bias,
    float* __restrict__ C) {
  extern __shared__ u16 sm[];  // 65536 u16 = 128 KiB

  const int tid = threadIdx.x;
  const int l = tid & 63;
  const int wid = tid >> 6;      // 0..7
  const int wr = wid >> 2;       // 0..1  (M halves of 128)
  const int wc = wid & 3;        // 0..3  (N quarters of 64)

  // XCD-bijective swizzle: 2048 blocks, 256/XCD == tiles/expert => expert==XCD
  const int id = blockIdx.x;
  const int swz = (id & 7) * 256 + (id >> 3);
  const int e = swz >> 8;
  const int rem = swz & 255;
  const int tn = rem >> 3;       // 0..31 (8 consecutive blocks share B-panel)
  const int tm = rem & 7;        // 0..7

  int off = 0;
  for (int i = 0; i < e; ++i) off += counts[i];
  const int row0 = off + tm * 256;
  const int col0 = tn * 256;
  const size_t wbase = (size_t)e * DOUT * DIN + (size_t)col0 * DIN;

  // -- staging per-lane constants (pre-swizzled global source, linear dest)
  const int rl = l >> 2;                     // row within 16-row slice
  const int q = (l & 3) ^ ((l >> 3) & 3);    // source k-granule (inverse swz)
  const int s0 = wid * 2, s1 = s0 + 1;       // this wave's 2 slices of 16
  const u16* pA0 = Xb + (size_t)(row0 + s0 * 16 + rl) * DIN + q * 8;
  const u16* pA1 = Xb + (size_t)(row0 + s1 * 16 + rl) * DIN + q * 8;
  const u16* pB0 = Wb + wbase + (size_t)(s0 * 16 + rl) * DIN + q * 8;
  const u16* pB1 = Wb + wbase + (size_t)(s1 * 16 + rl) * DIN + q * 8;

  // -- fragment-read per-lane constants (16x16 layout, r3-verified swizzle)
  const int f0 = ((l & 15) >> 1) & 3;
  const int gph = (l >> 4) ^ f0;             // physical granule 0..3
  const int aoff = (wr * 128 + (l & 15)) * 32 + gph * 8;
  const int boff = (wc * 64 + (l & 15)) * 32 + gph * 8;

  f32x4 acc[8][4] = {};
  short8 a[4], b[4];

#define SMA(buf, kh) (sm + (buf) * 32768 + (kh) * 8192)
#define SMB(buf, kh) (sm + (buf) * 32768 + 16384 + (kh) * 8192)
#define STAGE_A(buf, kt, kh) do { const int ko = (kt) * 64 + (kh) * 32; \
    GLOAD_LDS16(pA0 + ko, SMA(buf, kh) + s0 * 512);                     \
    GLOAD_LDS16(pA1 + ko, SMA(buf, kh) + s1 * 512); } while (0)
#define STAGE_B(buf, kt, kh) do { const int ko = (kt) * 64 + (kh) * 32; \
    GLOAD_LDS16(pB0 + ko, SMB(buf, kh) + s0 * 512);                     \
    GLOAD_LDS16(pB1 + ko, SMB(buf, kh) + s1 * 512); } while (0)
#define RA4(buf, kh, mb) do { _Pragma("unroll") for (int mf = 0; mf < 4; ++mf) \
    a[mf] = *(const short8*)(SMA(buf, kh) + aoff + ((mb) + mf) * 512); } while (0)
#define RB4(buf, kh) do { _Pragma("unroll") for (int nf = 0; nf < 4; ++nf) \
    b[nf] = *(const short8*)(SMB(buf, kh) + boff + nf * 512); } while (0)
#define FENCE() asm volatile("" ::: "memory")
#define BAR() do { FENCE(); __builtin_amdgcn_s_barrier(); FENCE(); } while (0)
#define SCHED0() __builtin_amdgcn_sched_barrier(0)
#define VMW(N) asm volatile("s_waitcnt vmcnt(" #N ")" ::: "memory")
#define LGKM0() asm volatile("s_waitcnt lgkmcnt(0)" ::: "memory")
#define MMQ(mb) do { __builtin_amdgcn_s_setprio(1);                                \
    _Pragma("unroll") for (int mf = 0; mf < 4; ++mf)                               \
      _Pragma("unroll") for (int nf = 0; nf < 4; ++nf)                             \
        acc[(mb) + mf][nf] =                                                       \
          __builtin_amdgcn_mfma_f32_16x16x32_bf16(a[mf], b[nf], acc[(mb) + mf][nf], 0, 0, 0); \
    __builtin_amdgcn_s_setprio(0); } while (0)

  const int NKT = DIN / 64;  // 32 K-tiles

  // prologue: tile 0 staged (kh0 first); VMW(4) publishes kh0, kh1 in flight.
  STAGE_A(0, 0, 0); STAGE_B(0, 0, 0); STAGE_A(0, 0, 1); STAGE_B(0, 0, 1);
  VMW(4);
  BAR();

  for (int kt = 0; kt < NKT; kt += 2) {
#define TILE(cur, nxt, t) do {                                          \
    const bool hn = (t) + 1 < NKT;                                      \
    /* ph1: kh0 m0-3 (12 reads; kh0 published at prior ph4-BAR) */      \
    RA4(cur, 0, 0); RB4(cur, 0);                                        \
    if (hn) STAGE_A(nxt, (t) + 1, 0);                                   \
    MMQ(0); SCHED0();   /* no hw barrier: nothing to publish */         \
    /* ph2: kh0 m4-7 ; VMW+BAR publishes cur-kh1 */                     \
    RA4(cur, 0, 4);                                                     \
    if (hn) { STAGE_B(nxt, (t) + 1, 0); VMW(4); } else VMW(0);          \
    BAR(); MMQ(4);                                                      \
    /* ph3: kh1 m0-3 (published at ph2-BAR) */                          \
    RA4(cur, 1, 0); RB4(cur, 1);                                        \
    if (hn) STAGE_A(nxt, (t) + 1, 1);                                   \
    MMQ(0); SCHED0();   /* no hw barrier: nothing to publish */         \
    /* ph4: kh1 m4-7 ; VMW+BAR publishes next-kh0 */                    \
    RA4(cur, 1, 4);                                                     \
    if (hn) { STAGE_B(nxt, (t) + 1, 1); VMW(4); }                       \
    BAR(); MMQ(4); } while (0)
    TILE(0, 1, kt);
    TILE(1, 0, kt + 1);
#undef TILE
  }

  // ---- epilogue: LDS repack -> coalesced nontemporal dwordx4 stores ----
  BAR();  // all K-loop LDS reads complete; LDS is now free scratch
  float* smf = (float*)sm;
  const int cbw = col0 + wc * 64;             // wave's 64-col span
  const int r0 = (l >> 4) << 2;               // acc row offset within frag
  const f32x4 bv4 = *(const f32x4*)(bias + (size_t)e * DOUT + cbw + (l & 15) * 4);

#pragma unroll
  for (int m = 0; m < 8; ++m) {
    float* eb = smf + (wid * 2 + (m & 1)) * 1088;   // 16x68 f32, dbuf'd
#pragma unroll
    for (int n = 0; n < 4; ++n) {
      const int c = n * 16 + (l & 15);
#pragma unroll
      for (int j = 0; j < 4; ++j)
        eb[(r0 + j) * 68 + c] = acc[m][n][j];
    }
    LGKM0();  // own writes visible (wave-private region)
    const int rbm = row0 + wr * 128 + m * 16;
#pragma unroll
    for (int i = 0; i < 4; ++i) {
      const int row = i * 4 + (l >> 4);
      f32x4 v = *(const f32x4*)(eb + row * 68 + (l & 15) * 4);
      v = v + bv4;
      __builtin_nontemporal_store(
          v, (f32x4*)(C + (size_t)(rbm + row) * DOUT + cbw + (l & 15) * 4));
    }
  }
}

// ---------------------------------------------------------------------------
// Fallback (ws too small): fused fp32->bf16 staging, 128x128 m97 structure.
// ---------------------------------------------------------------------------
__global__ __launch_bounds__(256) void moe_gemm_fused(
    const float* __restrict__ Xf, const float* __restrict__ Wf,
    const int* __restrict__ counts, const float* __restrict__ bias,
    float* __restrict__ C) {
  __shared__ __align__(16) u16 lds[2][2][128 * 32];

  const int tid = threadIdx.x;
  const int lane = tid & 63;
  const int wid = tid >> 6;
  const int wr = wid >> 1;
  const int wc = wid & 1;

  const int id = blockIdx.x;
  const int swz = (id & 7) * ((int)gridDim.x >> 3) + (id >> 3);
  const int e = swz >> 10;
  const int rem = swz & 1023;
  const int tn = rem >> 4;
  const int tml = rem & 15;

  int off = 0;
  for (int i = 0; i < e; ++i) off += counts[i];
  const int row0 = off + tml * 128;
  const int col0 = tn * 128;
  const size_t wbase = (size_t)e * DOUT * DIN + (size_t)col0 * DIN;

  f32x4 acc[4][4] = {};

  auto stage = [&](int buf, int kt) {
#pragma unroll
    for (int s = 0; s < 2; ++s) {
      int i = s * 256 + tid;
      int r = i >> 2, c = i & 3;
      const float* sa = Xf + (size_t)(row0 + r) * DIN + kt * 32 + c * 8;
      const float* sb = Wf + wbase + (size_t)r * DIN + kt * 32 + c * 8;
      f32x4 a0 = *(const f32x4*)sa;
      f32x4 a1 = *(const f32x4*)(sa + 4);
      f32x4 b0 = *(const f32x4*)sb;
      f32x4 b1 = *(const f32x4*)(sb + 4);
      short8 va, vb;
#pragma unroll
      for (int j = 0; j < 4; ++j) {
        va[j] = (short)f2bf(a0[j]); va[j + 4] = (short)f2bf(a1[j]);
        vb[j] = (short)f2bf(b0[j]); vb[j + 4] = (short)f2bf(b1[j]);
      }
      *(short8*)&lds[buf][0][i * 8] = va;
      *(short8*)&lds[buf][1][i * 8] = vb;
    }
  };

  auto compute = [&](int buf) {
    const int kc = lane >> 4;
    const int rr = lane & 15;
    short8 a[4], b[4];
    const u16* lA = lds[buf][0];
    const u16* lB = lds[buf][1];
#pragma unroll
    for (int m = 0; m < 4; ++m)
      a[m] = *(const short8*)(lA + (wr * 64 + m * 16 + rr) * 32 + kc * 8);
#pragma unroll
    for (int n = 0; n < 4; ++n)
      b[n] = *(const short8*)(lB + (wc * 64 + n * 16 + rr) * 32 + kc * 8);
#pragma unroll
    for (int m = 0; m < 4; ++m)
#pragma unroll
      for (int n = 0; n < 4; ++n)
        acc[m][n] = __builtin_amdgcn_mfma_f32_16x16x32_bf16(a[m], b[n], acc[m][n], 0, 0, 0);
  };

  stage(0, 0);
  for (int kt = 0; kt < DIN / 32; ++kt) {
    __syncthreads();
    if (kt + 1 < DIN / 32) stage((kt + 1) & 1, kt + 1);
    compute(kt & 1);
  }

  const int rbase = row0 + wr * 64;
  const int cbase = col0 + wc * 64;
#pragma unroll
  for (int n = 0; n < 4; ++n) {
    const int col = cbase + n * 16 + (lane & 15);
    const float bv = bias[e * DOUT + col];
#pragma unroll
    for (int m = 0; m < 4; ++m) {
      const int r0 = rbase + m * 16 + (lane >> 4) * 4;
#pragma unroll
      for (int j = 0; j < 4; ++j)
        C[(size_t)(r0 + j) * DOUT + col] = acc[m][n][j] + bv;
    }
  }
}

extern "C" void kernel_launch(void* const* d_in, const int* in_sizes, int n_in,
                              void* d_out, int out_size, void* d_ws, size_t ws_size,
                              hipStream_t stream) {
  const float* inp = (const float*)d_in[0];
  const int* counts = (const int*)d_in[1];
  const float* weight = (const float*)d_in[2];
  const float* bias = (const float*)d_in[3];
  float* out = (float*)d_out;

  const size_t nx = (size_t)NTOK * DIN;
  const size_t nw = (size_t)NE * DOUT * DIN;
  const size_t need = (nx + nw) * sizeof(u16);

  if (ws_size >= need) {
    u16* xb = (u16*)d_ws;
    u16* wb = xb + nx;
    cvt_f32_bf16<<<1024, 256, 0, stream>>>(inp, xb, nx);
    cvt_f32_bf16<<<4096, 256, 0, stream>>>(weight, wb, nw);
    const int grid = (NTOK / 256) * (DOUT / 256);  // 2048
    moe_gemm8<<<grid, 512, 131072, stream>>>(xb, wb, counts, bias, out);
  } else {
    const int grid = (NTOK / 128) * (DOUT / 128);  // 8192
    moe_gemm_fused<<<grid, 256, 0, stream>>>(inp, weight, counts, bias, out);
  }
}